// Round 10
// baseline (116.803 us; speedup 1.0000x reference)
//
#include <hip/hip_runtime.h>

constexpr int Bc = 2, Lc = 2048, Sc = 2048, Hc = 16, Ec = 64, Dc = 64;
constexpr int TILES = Sc / 64;            // 32 S-tiles
constexpr int NBH   = Bc * Hc;            // 32
constexpr size_t TILE_ELEMS = 4096;       // 64x64 bf16 tile
constexpr size_t ARR_ELEMS  = (size_t)NBH * TILES * TILE_ELEMS;   // 4,194,304
constexpr size_t WS_NEED    = ARR_ELEMS * 2 * 3;                  // 25,165,824 B

typedef float          f32x4  __attribute__((ext_vector_type(4)));
typedef float          f32x16 __attribute__((ext_vector_type(16)));
typedef __bf16         bf16x8 __attribute__((ext_vector_type(8)));
typedef unsigned short u16x8  __attribute__((ext_vector_type(8)));
typedef unsigned short u16x4  __attribute__((ext_vector_type(4)));
typedef unsigned int   u32x4  __attribute__((ext_vector_type(4)));

extern "C" __device__ float __ocml_native_exp2_f32(float);   // bare v_exp_f32

static __device__ __forceinline__ unsigned cvtpk(float lo, float hi) {
    unsigned r;
    asm("v_cvt_pk_bf16_f32 %0, %1, %2" : "=v"(r) : "v"(lo), "v"(hi));
    return r;
}

static __device__ __forceinline__ float fexp2(float x) {
    return __ocml_native_exp2_f32(x);
}

// ---------------------------------------------------------------------------
// Pre-pass: fp32 K1,K2,V1 -> bf16 tiles per (bh, stile), SLOT-MAJOR layout:
// 16B unit index = e8chunk*64 + row  (K rows = s; V rows = d, transposed).
// ---------------------------------------------------------------------------
__global__ __launch_bounds__(256) void prepass_kernel(
    const float* __restrict__ k1, const float* __restrict__ k2,
    const float* __restrict__ v1,
    unsigned short* __restrict__ k1b, unsigned short* __restrict__ k2b,
    unsigned short* __restrict__ vb)
{
    __shared__ unsigned short vt[64 * 80];

    const int blk = blockIdx.x;                // bh*32 + st
    const int st  = blk & 31;
    const int bh  = blk >> 5;
    const int b   = bh >> 4, h = bh & 15;
    const int s0  = st * 64;
    const size_t tileo = (size_t)blk * TILE_ELEMS;

    #pragma unroll
    for (int it = 0; it < 2; ++it) {
        int u  = threadIdx.x + it * 256;       // 0..511
        int s  = u >> 3, e8 = u & 7;
        size_t g = ((size_t)((b * Sc + s0 + s) * Hc + h)) * Ec + e8 * 8;

        float4 x0 = *reinterpret_cast<const float4*>(k1 + g);
        float4 x1 = *reinterpret_cast<const float4*>(k1 + g + 4);
        u32x4 o;
        o[0] = cvtpk(x0.x, x0.y); o[1] = cvtpk(x0.z, x0.w);
        o[2] = cvtpk(x1.x, x1.y); o[3] = cvtpk(x1.z, x1.w);
        *reinterpret_cast<u32x4*>(&k1b[tileo + (size_t)(e8 * 64 + s) * 8]) = o;

        x0 = *reinterpret_cast<const float4*>(k2 + g);
        x1 = *reinterpret_cast<const float4*>(k2 + g + 4);
        o[0] = cvtpk(x0.x, x0.y); o[1] = cvtpk(x0.z, x0.w);
        o[2] = cvtpk(x1.x, x1.y); o[3] = cvtpk(x1.z, x1.w);
        *reinterpret_cast<u32x4*>(&k2b[tileo + (size_t)(e8 * 64 + s) * 8]) = o;

        x0 = *reinterpret_cast<const float4*>(v1 + g);
        x1 = *reinterpret_cast<const float4*>(v1 + g + 4);
        o[0] = cvtpk(x0.x, x0.y); o[1] = cvtpk(x0.z, x0.w);
        o[2] = cvtpk(x1.x, x1.y); o[3] = cvtpk(x1.z, x1.w);
        *reinterpret_cast<u32x4*>(&vt[s * 80 + e8 * 8]) = o;   // row-major [s][d]
    }
    __syncthreads();

    #pragma unroll
    for (int it = 0; it < 2; ++it) {
        int u  = threadIdx.x + it * 256;
        int d  = u >> 3, sc8 = u & 7;
        u16x8 o;
        #pragma unroll
        for (int j = 0; j < 8; ++j) o[j] = vt[(sc8 * 8 + j) * 80 + d];  // column gather
        *reinterpret_cast<u16x8*>(&vb[tileo + (size_t)(sc8 * 64 + d) * 8]) = o;  // slot-major
    }
}

// ---------------------------------------------------------------------------
// Fused kernel, 32x32 MFMA, barrier-free, register-lean (target: 4 waves/SIMD).
// Q2 fragments live in LDS (wave-local stash, conflict-free [es][w][lane]
// u32x4 layout) and are re-read each tile, freeing 16 VGPRs. Per tile:
// load K1 -> QK1 -> t=exp2 (s1a dies) -> load K2 (reuse kf) -> QK2 (Q2 from
// LDS) -> load V -> activation -> in-reg P redistr (cvt_pk+permlane) -> PV.
// The LDS stash is reused as the s-half merge buffer after the final barrier.
// ---------------------------------------------------------------------------
__global__ __launch_bounds__(256, 4) void fused_kernel(
    const float* __restrict__ q1, const float* __restrict__ q2,
    const unsigned short* __restrict__ k1b, const unsigned short* __restrict__ k2b,
    const unsigned short* __restrict__ vb, float* __restrict__ out)
{
    __shared__ unsigned char smem[20480];         // 16 KiB Q2 stash / 20 KiB merge
    u32x4* qlds = reinterpret_cast<u32x4*>(smem);
    float* mbuf = reinterpret_cast<float*>(smem);

    const int orig    = blockIdx.x;
    const int logical = (orig & 7) * 128 + (orig >> 3);   // XCD swizzle (1024%8==0)
    const int lblk = logical & 31;
    const int bh   = logical >> 5;
    const int b    = bh >> 4, h = bh & 15;

    const int tid  = threadIdx.x;
    const int w    = tid >> 6;
    const int lane = tid & 63;
    const int l31  = lane & 31;
    const int hi   = lane >> 5;
    const int qsub = w >> 1;       // 0,1 : which 32-q subblock
    const int sh   = w & 1;        // 0,1 : which 32-s half of each tile

    // ---- Q fragments (col=lane&31=q, k=8*hi+j=e), scale*log2e folded.
    //      qa1 stays in registers; qa2 goes to the LDS stash. ----
    constexpr float C1 = 0.36067376022224085f;    // 2*(1/8)*log2(e)
    constexpr float C2 = -0.18033688011112043f;   // -(1/8)*log2(e)
    const int    qrow  = lblk * 64 + qsub * 32 + l31;
    const size_t qbase = ((size_t)((b * Lc + qrow) * Hc + h)) * Ec;
    u32x4 qa1[4];
    #pragma unroll
    for (int es = 0; es < 4; ++es) {
        const float* p1 = q1 + qbase + es * 16 + hi * 8;
        float4 x0 = *reinterpret_cast<const float4*>(p1);
        float4 x1 = *reinterpret_cast<const float4*>(p1 + 4);
        qa1[es] = (u32x4){cvtpk(x0.x * C1, x0.y * C1), cvtpk(x0.z * C1, x0.w * C1),
                          cvtpk(x1.x * C1, x1.y * C1), cvtpk(x1.z * C1, x1.w * C1)};
    }
    #pragma unroll
    for (int es = 0; es < 4; ++es) {
        const float* p2 = q2 + qbase + es * 16 + hi * 8;
        float4 x0 = *reinterpret_cast<const float4*>(p2);
        float4 x1 = *reinterpret_cast<const float4*>(p2 + 4);
        u32x4 v = (u32x4){cvtpk(x0.x * C2, x0.y * C2), cvtpk(x0.z * C2, x0.w * C2),
                          cvtpk(x1.x * C2, x1.y * C2), cvtpk(x1.z * C2, x1.w * C2)};
        qlds[es * 256 + w * 64 + lane] = v;       // wave-local; no barrier needed
    }

    f32x16 acc0 = {}, acc1 = {};                 // PV accumulators (d 0-31, 32-63)

    // Per-lane fragment base offsets (elems); per-es / per-(dt,ks) deltas fold
    // into load immediate offsets.
    const int srow  = sh * 32 + l31;
    const int kofs0 = (hi * 64 + srow) * 8;                    // + es*1024
    const int vofs0 = ((sh * 4 + hi) * 64 + l31) * 8;          // + dt*256 + ks*1024

    const unsigned short* kt1 = k1b + (size_t)bh * TILES * TILE_ELEMS + kofs0;
    const unsigned short* kt2 = k2b + (size_t)bh * TILES * TILE_ELEMS + kofs0;
    const unsigned short* vt  = vb  + (size_t)bh * TILES * TILE_ELEMS + vofs0;

    for (int st = 0; st < TILES; ++st) {
        // ---- K1 loads + QK1 ----
        u16x8 kf[4];
        #pragma unroll
        for (int es = 0; es < 4; ++es)
            kf[es] = *reinterpret_cast<const u16x8*>(kt1 + es * 1024);

        f32x16 s1a = {};
        __builtin_amdgcn_s_setprio(1);
        #pragma unroll
        for (int es = 0; es < 4; ++es)
            s1a = __builtin_amdgcn_mfma_f32_32x32x16_bf16(
                __builtin_bit_cast(bf16x8, kf[es]),
                __builtin_bit_cast(bf16x8, qa1[es]), s1a, 0, 0, 0);
        __builtin_amdgcn_s_setprio(0);

        // ---- t = 2^{s1a} in place (frees s1a before s2a is live) ----
        float tt[16];
        #pragma unroll
        for (int i = 0; i < 16; ++i) tt[i] = fexp2(s1a[i]);

        // ---- K2 loads (reuse kf regs) + QK2 (Q2 from LDS stash) ----
        #pragma unroll
        for (int es = 0; es < 4; ++es)
            kf[es] = *reinterpret_cast<const u16x8*>(kt2 + es * 1024);

        f32x16 s2a = {};
        __builtin_amdgcn_s_setprio(1);
        #pragma unroll
        for (int es = 0; es < 4; ++es) {
            u32x4 q2f = qlds[es * 256 + w * 64 + lane];
            s2a = __builtin_amdgcn_mfma_f32_32x32x16_bf16(
                __builtin_bit_cast(bf16x8, kf[es]),
                __builtin_bit_cast(bf16x8, q2f), s2a, 0, 0, 0);
        }
        __builtin_amdgcn_s_setprio(0);

        // ---- V loads (latency covered by activation below) ----
        u16x8 vfr[4];
        #pragma unroll
        for (int dt = 0; dt < 2; ++dt)
            #pragma unroll
            for (int ks = 0; ks < 2; ++ks)
                vfr[dt * 2 + ks] = *reinterpret_cast<const u16x8*>(vt + dt * 256 + ks * 1024);

        // ---- activation: u=2^{s2a}; p=(t-1)/((t+1)(1+u)); shared rcp per 4 ----
        unsigned pw[8];
        #pragma unroll
        for (int c = 0; c < 4; ++c) {
            float dn[4], p[4];
            #pragma unroll
            for (int j = 0; j < 4; ++j) {
                float u = fexp2(s2a[4 * c + j]);
                dn[j] = __builtin_fmaf(tt[4 * c + j], u, tt[4 * c + j]) + (u + 1.f);
            }
            float d01 = dn[0] * dn[1];
            float d23 = dn[2] * dn[3];
            float inv = __builtin_amdgcn_rcpf(d01 * d23);
            float i01 = inv * d23, i23 = inv * d01;
            p[0] = (tt[4 * c + 0] - 1.f) * (dn[1] * i01);
            p[1] = (tt[4 * c + 1] - 1.f) * (dn[0] * i01);
            p[2] = (tt[4 * c + 2] - 1.f) * (dn[3] * i23);
            p[3] = (tt[4 * c + 3] - 1.f) * (dn[2] * i23);
            pw[2 * c]     = cvtpk(p[0], p[1]);
            pw[2 * c + 1] = cvtpk(p[2], p[3]);
        }

        // ---- in-register P redistribution + PV ----
        __builtin_amdgcn_s_setprio(1);
        #pragma unroll
        for (int ks = 0; ks < 2; ++ks) {
            unsigned A0 = pw[4 * ks + 0];
            unsigned A1 = pw[4 * ks + 1];
            unsigned B0 = pw[4 * ks + 2];
            unsigned B1 = pw[4 * ks + 3];
            asm("v_permlane32_swap_b32 %0, %1" : "+v"(A0), "+v"(B0));
            asm("v_permlane32_swap_b32 %0, %1" : "+v"(A1), "+v"(B1));
            bf16x8 pa = __builtin_bit_cast(bf16x8, (u32x4){A0, A1, B0, B1});
            acc0 = __builtin_amdgcn_mfma_f32_32x32x16_bf16(pa, __builtin_bit_cast(bf16x8, vfr[ks]),     acc0, 0, 0, 0);
            acc1 = __builtin_amdgcn_mfma_f32_32x32x16_bf16(pa, __builtin_bit_cast(bf16x8, vfr[2 + ks]), acc1, 0, 0, 0);
        }
        __builtin_amdgcn_s_setprio(0);

        kt1 += TILE_ELEMS; kt2 += TILE_ELEMS; vt += TILE_ELEMS;
    }

    // ---- merge s-halves through LDS (smem reused) + epilogue ----
    __syncthreads();                              // all Q2 stash reads are done
    if (sh == 1) {
        #pragma unroll
        for (int r4 = 0; r4 < 4; ++r4) {
            *reinterpret_cast<f32x4*>(&mbuf[(qsub * 2 + 0) * 1280 + lane * 20 + r4 * 4]) =
                (f32x4){acc0[r4 * 4 + 0], acc0[r4 * 4 + 1], acc0[r4 * 4 + 2], acc0[r4 * 4 + 3]};
            *reinterpret_cast<f32x4*>(&mbuf[(qsub * 2 + 1) * 1280 + lane * 20 + r4 * 4]) =
                (f32x4){acc1[r4 * 4 + 0], acc1[r4 * 4 + 1], acc1[r4 * 4 + 2], acc1[r4 * 4 + 3]};
        }
    }
    __syncthreads();
    if (sh == 0) {
        #pragma unroll
        for (int dt = 0; dt < 2; ++dt) {
            float m[16];
            #pragma unroll
            for (int r4 = 0; r4 < 4; ++r4) {
                f32x4 v = *reinterpret_cast<const f32x4*>(&mbuf[(qsub * 2 + dt) * 1280 + lane * 20 + r4 * 4]);
                m[r4 * 4 + 0] = v[0]; m[r4 * 4 + 1] = v[1]; m[r4 * 4 + 2] = v[2]; m[r4 * 4 + 3] = v[3];
            }
            #pragma unroll
            for (int r = 0; r < 16; ++r) {
                float val = m[r] + (dt == 0 ? acc0[r] : acc1[r]);
                int q = lblk * 64 + qsub * 32 + (r & 3) + 8 * (r >> 2) + 4 * hi;
                out[((size_t)(b * Lc + q) * Hc + h) * Dc + dt * 32 + l31] = val;
            }
        }
    }
}

// ---------------------------------------------------------------------------
// Fallback (round-1 kernel, proven correct) if ws_size is too small.
// ---------------------------------------------------------------------------
static __device__ __forceinline__ unsigned short f2bf(float f) {
    unsigned u = __builtin_bit_cast(unsigned, f);
    u += 0x7fffu + ((u >> 16) & 1u);
    return (unsigned short)(u >> 16);
}

__global__ __launch_bounds__(256) void fallback_kernel(
    const float* __restrict__ q1, const float* __restrict__ k1,
    const float* __restrict__ v1, const float* __restrict__ q2,
    const float* __restrict__ k2, float* __restrict__ out)
{
    constexpr int KSTR = 72, VSTR = 88, PSTR = 88;
    __shared__ unsigned short k1t[64 * KSTR];
    __shared__ unsigned short k2t[64 * KSTR];
    __shared__ unsigned short vtt[64 * VSTR];
    __shared__ unsigned short pt [4 * 16 * PSTR];

    const int blk  = blockIdx.x;
    const int lblk = blk & 31;
    const int bh   = blk >> 5;
    const int b    = bh >> 4;
    const int h    = bh & 15;
    const int tid  = threadIdx.x;
    const int w    = tid >> 6;
    const int lane = tid & 63;
    const int lr   = lane & 15;
    const int lg   = lane >> 4;

    const int    qrow  = lblk * 64 + w * 16 + lr;
    const size_t qbase = ((size_t)(b * Lc + qrow) * Hc + h) * Ec;
    bf16x8 a1[2], a2[2];
    for (int es = 0; es < 2; ++es) {
        u16x8 t1, t2;
        for (int j = 0; j < 8; ++j) {
            t1[j] = f2bf(q1[qbase + es * 32 + lg * 8 + j]);
            t2[j] = f2bf(q2[qbase + es * 32 + lg * 8 + j]);
        }
        a1[es] = __builtin_bit_cast(bf16x8, t1);
        a2[es] = __builtin_bit_cast(bf16x8, t2);
    }
    f32x4 acc[4];
    for (int i = 0; i < 4; ++i) acc[i] = (f32x4){0.f, 0.f, 0.f, 0.f};
    constexpr float CT = 0.25f, CS = -0.125f;

    for (int s0 = 0; s0 < Sc; s0 += 64) {
        for (int it = 0; it < 4; ++it) {
            int idx = tid + it * 256;
            int sr  = idx >> 4;
            int c4  = (idx & 15) << 2;
            size_t gk = ((size_t)(b * Sc + s0 + sr) * Hc + h) * Ec + c4;
            float4 x1 = *reinterpret_cast<const float4*>(k1 + gk);
            float4 x2 = *reinterpret_cast<const float4*>(k2 + gk);
            float4 xv = *reinterpret_cast<const float4*>(v1 + gk);
            u16x4 o1, o2;
            o1[0]=f2bf(x1.x); o1[1]=f2bf(x1.y); o1[2]=f2bf(x1.z); o1[3]=f2bf(x1.w);
            o2[0]=f2bf(x2.x); o2[1]=f2bf(x2.y); o2[2]=f2bf(x2.z); o2[3]=f2bf(x2.w);
            *reinterpret_cast<u16x4*>(&k1t[sr * KSTR + c4]) = o1;
            *reinterpret_cast<u16x4*>(&k2t[sr * KSTR + c4]) = o2;
            vtt[(c4 + 0) * VSTR + sr] = f2bf(xv.x);
            vtt[(c4 + 1) * VSTR + sr] = f2bf(xv.y);
            vtt[(c4 + 2) * VSTR + sr] = f2bf(xv.z);
            vtt[(c4 + 3) * VSTR + sr] = f2bf(xv.w);
        }
        __syncthreads();
        for (int ct = 0; ct < 4; ++ct) {
            f32x4 s1 = {0.f,0.f,0.f,0.f}, s2 = {0.f,0.f,0.f,0.f};
            for (int es = 0; es < 2; ++es) {
                bf16x8 b1 = __builtin_bit_cast(bf16x8,
                    *reinterpret_cast<const u16x8*>(&k1t[(ct*16 + lr) * KSTR + es*32 + lg*8]));
                bf16x8 b2 = __builtin_bit_cast(bf16x8,
                    *reinterpret_cast<const u16x8*>(&k2t[(ct*16 + lr) * KSTR + es*32 + lg*8]));
                s1 = __builtin_amdgcn_mfma_f32_16x16x32_bf16(a1[es], b1, s1, 0, 0, 0);
                s2 = __builtin_amdgcn_mfma_f32_16x16x32_bf16(a2[es], b2, s2, 0, 0, 0);
            }
            for (int i = 0; i < 4; ++i) {
                float xa = fminf(fmaxf(s1[i] * CT, -30.f), 30.f);
                float xb = fminf(fmaxf(s2[i] * CS, -30.f), 30.f);
                float t  = __expf(xa);
                float u  = __expf(xb);
                float p  = (t - 1.f) * __builtin_amdgcn_rcpf((t + 1.f) * (1.f + u));
                pt[(w*16 + lg*4 + i) * PSTR + ct*16 + lr] = f2bf(p);
            }
        }
        asm volatile("s_waitcnt lgkmcnt(0)" ::: "memory");
        for (int ks = 0; ks < 2; ++ks) {
            bf16x8 pa = __builtin_bit_cast(bf16x8,
                *reinterpret_cast<const u16x8*>(&pt[(w*16 + lr) * PSTR + ks*32 + lg*8]));
            for (int dt = 0; dt < 4; ++dt) {
                bf16x8 vf = __builtin_bit_cast(bf16x8,
                    *reinterpret_cast<const u16x8*>(&vtt[(dt*16 + lr) * VSTR + ks*32 + lg*8]));
                acc[dt] = __builtin_amdgcn_mfma_f32_16x16x32_bf16(pa, vf, acc[dt], 0, 0, 0);
            }
        }
        __syncthreads();
    }
    const int orow = lblk * 64 + w * 16;
    for (int dt = 0; dt < 4; ++dt)
        for (int i = 0; i < 4; ++i) {
            int l = orow + lg * 4 + i;
            out[((size_t)(b * Lc + l) * Hc + h) * Dc + dt * 16 + lr] = acc[dt][i];
        }
}

extern "C" void kernel_launch(void* const* d_in, const int* in_sizes, int n_in,
                              void* d_out, int out_size, void* d_ws, size_t ws_size,
                              hipStream_t stream) {
    const float* q1 = (const float*)d_in[0];
    const float* k1 = (const float*)d_in[1];
    const float* v1 = (const float*)d_in[2];
    const float* q2 = (const float*)d_in[3];
    const float* k2 = (const float*)d_in[4];
    float* out = (float*)d_out;

    if (ws_size >= WS_NEED) {
        unsigned short* k1b = (unsigned short*)d_ws;
        unsigned short* k2b = k1b + ARR_ELEMS;
        unsigned short* vbp = k2b + ARR_ELEMS;
        prepass_kernel<<<dim3(NBH * TILES), dim3(256), 0, stream>>>(k1, k2, v1, k1b, k2b, vbp);
        fused_kernel<<<dim3(NBH * TILES), dim3(256), 0, stream>>>(q1, q2, k1b, k2b, vbp, out);
    } else {
        fallback_kernel<<<dim3(NBH * TILES), dim3(256), 0, stream>>>(q1, k1, v1, q2, k2, out);
    }
}

// Round 12
// 99.144 us; speedup vs baseline: 1.1781x; 1.1781x over previous
//
#include <hip/hip_runtime.h>

constexpr int Bc = 2, Lc = 2048, Sc = 2048, Hc = 16, Ec = 64, Dc = 64;
constexpr int TILES = Sc / 64;            // 32 S-tiles
constexpr int NBH   = Bc * Hc;            // 32
constexpr size_t TILE_ELEMS = 4096;       // 64x64 bf16 tile
constexpr size_t ARR_ELEMS  = (size_t)NBH * TILES * TILE_ELEMS;   // 4,194,304
constexpr size_t WS_NEED    = ARR_ELEMS * 2 * 3;                  // 25,165,824 B

typedef float          f32x4  __attribute__((ext_vector_type(4)));
typedef float          f32x16 __attribute__((ext_vector_type(16)));
typedef __bf16         bf16x8 __attribute__((ext_vector_type(8)));
typedef unsigned short u16x8  __attribute__((ext_vector_type(8)));
typedef unsigned short u16x4  __attribute__((ext_vector_type(4)));
typedef unsigned int   u32x4  __attribute__((ext_vector_type(4)));

extern "C" __device__ float __ocml_native_exp2_f32(float);   // bare v_exp_f32

static __device__ __forceinline__ unsigned cvtpk(float lo, float hi) {
    unsigned r;
    asm("v_cvt_pk_bf16_f32 %0, %1, %2" : "=v"(r) : "v"(lo), "v"(hi));
    return r;
}

static __device__ __forceinline__ float fexp2(float x) {
    return __ocml_native_exp2_f32(x);
}

// ---------------------------------------------------------------------------
// Pre-pass: fp32 K1,K2,V1 -> bf16 tiles per (bh, stile), SLOT-MAJOR layout:
// 16B unit index = e8chunk*64 + row  (K rows = s; V rows = d, transposed).
// ---------------------------------------------------------------------------
__global__ __launch_bounds__(256) void prepass_kernel(
    const float* __restrict__ k1, const float* __restrict__ k2,
    const float* __restrict__ v1,
    unsigned short* __restrict__ k1b, unsigned short* __restrict__ k2b,
    unsigned short* __restrict__ vb)
{
    __shared__ unsigned short vt[64 * 80];

    const int blk = blockIdx.x;                // bh*32 + st
    const int st  = blk & 31;
    const int bh  = blk >> 5;
    const int b   = bh >> 4, h = bh & 15;
    const int s0  = st * 64;
    const size_t tileo = (size_t)blk * TILE_ELEMS;

    #pragma unroll
    for (int it = 0; it < 2; ++it) {
        int u  = threadIdx.x + it * 256;       // 0..511
        int s  = u >> 3, e8 = u & 7;
        size_t g = ((size_t)((b * Sc + s0 + s) * Hc + h)) * Ec + e8 * 8;

        float4 x0 = *reinterpret_cast<const float4*>(k1 + g);
        float4 x1 = *reinterpret_cast<const float4*>(k1 + g + 4);
        u32x4 o;
        o[0] = cvtpk(x0.x, x0.y); o[1] = cvtpk(x0.z, x0.w);
        o[2] = cvtpk(x1.x, x1.y); o[3] = cvtpk(x1.z, x1.w);
        *reinterpret_cast<u32x4*>(&k1b[tileo + (size_t)(e8 * 64 + s) * 8]) = o;

        x0 = *reinterpret_cast<const float4*>(k2 + g);
        x1 = *reinterpret_cast<const float4*>(k2 + g + 4);
        o[0] = cvtpk(x0.x, x0.y); o[1] = cvtpk(x0.z, x0.w);
        o[2] = cvtpk(x1.x, x1.y); o[3] = cvtpk(x1.z, x1.w);
        *reinterpret_cast<u32x4*>(&k2b[tileo + (size_t)(e8 * 64 + s) * 8]) = o;

        x0 = *reinterpret_cast<const float4*>(v1 + g);
        x1 = *reinterpret_cast<const float4*>(v1 + g + 4);
        o[0] = cvtpk(x0.x, x0.y); o[1] = cvtpk(x0.z, x0.w);
        o[2] = cvtpk(x1.x, x1.y); o[3] = cvtpk(x1.z, x1.w);
        *reinterpret_cast<u32x4*>(&vt[s * 80 + e8 * 8]) = o;   // row-major [s][d]
    }
    __syncthreads();

    #pragma unroll
    for (int it = 0; it < 2; ++it) {
        int u  = threadIdx.x + it * 256;
        int d  = u >> 3, sc8 = u & 7;
        u16x8 o;
        #pragma unroll
        for (int j = 0; j < 8; ++j) o[j] = vt[(sc8 * 8 + j) * 80 + d];  // column gather
        *reinterpret_cast<u16x8*>(&vb[tileo + (size_t)(sc8 * 64 + d) * 8]) = o;  // slot-major
    }
}

// ---------------------------------------------------------------------------
// Fused kernel, 32x32 MFMA, barrier-free, SOFTWARE-PIPELINED (r7 structure):
//   QK1+QK2 (kf prefetched last iter) -> issue V(st) -> issue K(st+1) ->
//   activation -> in-reg P redistribution (cvt_pk+permlane32_swap) -> PV.
// Lean addressing: per-lane pre-offset pointers, constant deltas fold into
// load immediates. No LDS in the main loop; merge buffer only at the end.
// ---------------------------------------------------------------------------
__global__ __launch_bounds__(256, 3) void fused_kernel(
    const float* __restrict__ q1, const float* __restrict__ q2,
    const unsigned short* __restrict__ k1b, const unsigned short* __restrict__ k2b,
    const unsigned short* __restrict__ vb, float* __restrict__ out)
{
    __shared__ float mbuf[4 * 1280];              // 20 KiB merge buffer

    const int orig    = blockIdx.x;
    const int logical = (orig & 7) * 128 + (orig >> 3);   // XCD swizzle (1024%8==0)
    const int lblk = logical & 31;
    const int bh   = logical >> 5;
    const int b    = bh >> 4, h = bh & 15;

    const int tid  = threadIdx.x;
    const int w    = tid >> 6;
    const int lane = tid & 63;
    const int l31  = lane & 31;
    const int hi   = lane >> 5;
    const int qsub = w >> 1;       // 0,1 : which 32-q subblock
    const int sh   = w & 1;        // 0,1 : which 32-s half of each tile

    // ---- Q B-fragments (col=lane&31=q, k=8*hi+j=e), scale*log2e folded ----
    constexpr float C1 = 0.36067376022224085f;    // 2*(1/8)*log2(e)
    constexpr float C2 = -0.18033688011112043f;   // -(1/8)*log2(e)
    const int    qrow  = lblk * 64 + qsub * 32 + l31;
    const size_t qbase = ((size_t)((b * Lc + qrow) * Hc + h)) * Ec;
    u32x4 qa1[4], qa2[4];
    #pragma unroll
    for (int es = 0; es < 4; ++es) {
        const float* p1 = q1 + qbase + es * 16 + hi * 8;
        const float* p2 = q2 + qbase + es * 16 + hi * 8;
        float4 x0 = *reinterpret_cast<const float4*>(p1);
        float4 x1 = *reinterpret_cast<const float4*>(p1 + 4);
        qa1[es] = (u32x4){cvtpk(x0.x * C1, x0.y * C1), cvtpk(x0.z * C1, x0.w * C1),
                          cvtpk(x1.x * C1, x1.y * C1), cvtpk(x1.z * C1, x1.w * C1)};
        x0 = *reinterpret_cast<const float4*>(p2);
        x1 = *reinterpret_cast<const float4*>(p2 + 4);
        qa2[es] = (u32x4){cvtpk(x0.x * C2, x0.y * C2), cvtpk(x0.z * C2, x0.w * C2),
                          cvtpk(x1.x * C2, x1.y * C2), cvtpk(x1.z * C2, x1.w * C2)};
    }

    f32x16 acc0 = {}, acc1 = {};                 // PV accumulators (d 0-31, 32-63)

    // Per-lane pre-offset pointers; per-es / per-(dt,ks) deltas are constant.
    const int srow  = sh * 32 + l31;
    const int kofs0 = (hi * 64 + srow) * 8;                    // + es*1024
    const int vofs0 = ((sh * 4 + hi) * 64 + l31) * 8;          // + dt*256 + ks*1024

    const unsigned short* kt1 = k1b + (size_t)bh * TILES * TILE_ELEMS + kofs0;
    const unsigned short* kt2 = k2b + (size_t)bh * TILES * TILE_ELEMS + kofs0;
    const unsigned short* vt  = vb  + (size_t)bh * TILES * TILE_ELEMS + vofs0;

    // ---- prologue: K loads for tile 0 ----
    u16x8 kf1[4], kf2[4], vfr[4];
    #pragma unroll
    for (int es = 0; es < 4; ++es) {
        kf1[es] = *reinterpret_cast<const u16x8*>(kt1 + es * 1024);
        kf2[es] = *reinterpret_cast<const u16x8*>(kt2 + es * 1024);
    }

    for (int st = 0; st < TILES; ++st) {
        // ---- QK1 + QK2 (two independent MFMA chains, prefetched operands) ----
        f32x16 s1a = {}, s2a = {};
        __builtin_amdgcn_s_setprio(1);
        #pragma unroll
        for (int es = 0; es < 4; ++es) {
            s1a = __builtin_amdgcn_mfma_f32_32x32x16_bf16(
                __builtin_bit_cast(bf16x8, kf1[es]),
                __builtin_bit_cast(bf16x8, qa1[es]), s1a, 0, 0, 0);
            s2a = __builtin_amdgcn_mfma_f32_32x32x16_bf16(
                __builtin_bit_cast(bf16x8, kf2[es]),
                __builtin_bit_cast(bf16x8, qa2[es]), s2a, 0, 0, 0);
        }
        __builtin_amdgcn_s_setprio(0);

        // ---- issue V(st) loads FIRST (older than K -> PV wait leaves K flying) ----
        #pragma unroll
        for (int dt = 0; dt < 2; ++dt)
            #pragma unroll
            for (int ks = 0; ks < 2; ++ks)
                vfr[dt * 2 + ks] = *reinterpret_cast<const u16x8*>(vt + dt * 256 + ks * 1024);

        // ---- issue K(st+1) loads (land during activation+PV) ----
        if (st + 1 < TILES) {
            #pragma unroll
            for (int es = 0; es < 4; ++es) {
                kf1[es] = *reinterpret_cast<const u16x8*>(kt1 + TILE_ELEMS + es * 1024);
                kf2[es] = *reinterpret_cast<const u16x8*>(kt2 + TILE_ELEMS + es * 1024);
            }
        }

        // ---- activation: tp1=2^{s1}+1; u=2^{s2}; dn=fma(tp1,u,tp1);
        //      p=(tp1-2)*rcp(dn)   (covers V + K load latency) ----
        float p[16];
        #pragma unroll
        for (int i = 0; i < 16; ++i) {
            float tp1 = fexp2(s1a[i]) + 1.f;      // e^{2*scale*score1} + 1
            float uu  = fexp2(s2a[i]);            // e^{-scale*score2}
            float dn  = __builtin_fmaf(tp1, uu, tp1);   // (t+1)(1+u)
            p[i] = (tp1 - 2.f) * __builtin_amdgcn_rcpf(dn);
        }

        // ---- in-register P redistribution + PV ----
        __builtin_amdgcn_s_setprio(1);
        #pragma unroll
        for (int ks = 0; ks < 2; ++ks) {
            unsigned A0 = cvtpk(p[8 * ks + 0], p[8 * ks + 1]);
            unsigned A1 = cvtpk(p[8 * ks + 2], p[8 * ks + 3]);
            unsigned B0 = cvtpk(p[8 * ks + 4], p[8 * ks + 5]);
            unsigned B1 = cvtpk(p[8 * ks + 6], p[8 * ks + 7]);
            asm("v_permlane32_swap_b32 %0, %1" : "+v"(A0), "+v"(B0));
            asm("v_permlane32_swap_b32 %0, %1" : "+v"(A1), "+v"(B1));
            bf16x8 pa = __builtin_bit_cast(bf16x8, (u32x4){A0, A1, B0, B1});
            acc0 = __builtin_amdgcn_mfma_f32_32x32x16_bf16(pa, __builtin_bit_cast(bf16x8, vfr[ks]),     acc0, 0, 0, 0);
            acc1 = __builtin_amdgcn_mfma_f32_32x32x16_bf16(pa, __builtin_bit_cast(bf16x8, vfr[2 + ks]), acc1, 0, 0, 0);
        }
        __builtin_amdgcn_s_setprio(0);

        kt1 += TILE_ELEMS; kt2 += TILE_ELEMS; vt += TILE_ELEMS;
    }

    // ---- merge s-halves through LDS + epilogue ----
    __syncthreads();
    if (sh == 1) {
        #pragma unroll
        for (int r4 = 0; r4 < 4; ++r4) {
            *reinterpret_cast<f32x4*>(&mbuf[(qsub * 2 + 0) * 1280 + lane * 20 + r4 * 4]) =
                (f32x4){acc0[r4 * 4 + 0], acc0[r4 * 4 + 1], acc0[r4 * 4 + 2], acc0[r4 * 4 + 3]};
            *reinterpret_cast<f32x4*>(&mbuf[(qsub * 2 + 1) * 1280 + lane * 20 + r4 * 4]) =
                (f32x4){acc1[r4 * 4 + 0], acc1[r4 * 4 + 1], acc1[r4 * 4 + 2], acc1[r4 * 4 + 3]};
        }
    }
    __syncthreads();
    if (sh == 0) {
        #pragma unroll
        for (int dt = 0; dt < 2; ++dt) {
            float m[16];
            #pragma unroll
            for (int r4 = 0; r4 < 4; ++r4) {
                f32x4 v = *reinterpret_cast<const f32x4*>(&mbuf[(qsub * 2 + dt) * 1280 + lane * 20 + r4 * 4]);
                m[r4 * 4 + 0] = v[0]; m[r4 * 4 + 1] = v[1]; m[r4 * 4 + 2] = v[2]; m[r4 * 4 + 3] = v[3];
            }
            #pragma unroll
            for (int r = 0; r < 16; ++r) {
                float val = m[r] + (dt == 0 ? acc0[r] : acc1[r]);
                int q = lblk * 64 + qsub * 32 + (r & 3) + 8 * (r >> 2) + 4 * hi;
                out[((size_t)(b * Lc + q) * Hc + h) * Dc + dt * 32 + l31] = val;
            }
        }
    }
}

// ---------------------------------------------------------------------------
// Fallback (round-1 kernel, proven correct) if ws_size is too small.
// ---------------------------------------------------------------------------
static __device__ __forceinline__ unsigned short f2bf(float f) {
    unsigned u = __builtin_bit_cast(unsigned, f);
    u += 0x7fffu + ((u >> 16) & 1u);
    return (unsigned short)(u >> 16);
}

__global__ __launch_bounds__(256) void fallback_kernel(
    const float* __restrict__ q1, const float* __restrict__ k1,
    const float* __restrict__ v1, const float* __restrict__ q2,
    const float* __restrict__ k2, float* __restrict__ out)
{
    constexpr int KSTR = 72, VSTR = 88, PSTR = 88;
    __shared__ unsigned short k1t[64 * KSTR];
    __shared__ unsigned short k2t[64 * KSTR];
    __shared__ unsigned short vtt[64 * VSTR];
    __shared__ unsigned short pt [4 * 16 * PSTR];

    const int blk  = blockIdx.x;
    const int lblk = blk & 31;
    const int bh   = blk >> 5;
    const int b    = bh >> 4;
    const int h    = bh & 15;
    const int tid  = threadIdx.x;
    const int w    = tid >> 6;
    const int lane = tid & 63;
    const int lr   = lane & 15;
    const int lg   = lane >> 4;

    const int    qrow  = lblk * 64 + w * 16 + lr;
    const size_t qbase = ((size_t)(b * Lc + qrow) * Hc + h) * Ec;
    bf16x8 a1[2], a2[2];
    for (int es = 0; es < 2; ++es) {
        u16x8 t1, t2;
        for (int j = 0; j < 8; ++j) {
            t1[j] = f2bf(q1[qbase + es * 32 + lg * 8 + j]);
            t2[j] = f2bf(q2[qbase + es * 32 + lg * 8 + j]);
        }
        a1[es] = __builtin_bit_cast(bf16x8, t1);
        a2[es] = __builtin_bit_cast(bf16x8, t2);
    }
    f32x4 acc[4];
    for (int i = 0; i < 4; ++i) acc[i] = (f32x4){0.f, 0.f, 0.f, 0.f};
    constexpr float CT = 0.25f, CS = -0.125f;

    for (int s0 = 0; s0 < Sc; s0 += 64) {
        for (int it = 0; it < 4; ++it) {
            int idx = tid + it * 256;
            int sr  = idx >> 4;
            int c4  = (idx & 15) << 2;
            size_t gk = ((size_t)(b * Sc + s0 + sr) * Hc + h) * Ec + c4;
            float4 x1 = *reinterpret_cast<const float4*>(k1 + gk);
            float4 x2 = *reinterpret_cast<const float4*>(k2 + gk);
            float4 xv = *reinterpret_cast<const float4*>(v1 + gk);
            u16x4 o1, o2;
            o1[0]=f2bf(x1.x); o1[1]=f2bf(x1.y); o1[2]=f2bf(x1.z); o1[3]=f2bf(x1.w);
            o2[0]=f2bf(x2.x); o2[1]=f2bf(x2.y); o2[2]=f2bf(x2.z); o2[3]=f2bf(x2.w);
            *reinterpret_cast<u16x4*>(&k1t[sr * KSTR + c4]) = o1;
            *reinterpret_cast<u16x4*>(&k2t[sr * KSTR + c4]) = o2;
            vtt[(c4 + 0) * VSTR + sr] = f2bf(xv.x);
            vtt[(c4 + 1) * VSTR + sr] = f2bf(xv.y);
            vtt[(c4 + 2) * VSTR + sr] = f2bf(xv.z);
            vtt[(c4 + 3) * VSTR + sr] = f2bf(xv.w);
        }
        __syncthreads();
        for (int ct = 0; ct < 4; ++ct) {
            f32x4 s1 = {0.f,0.f,0.f,0.f}, s2 = {0.f,0.f,0.f,0.f};
            for (int es = 0; es < 2; ++es) {
                bf16x8 b1 = __builtin_bit_cast(bf16x8,
                    *reinterpret_cast<const u16x8*>(&k1t[(ct*16 + lr) * KSTR + es*32 + lg*8]));
                bf16x8 b2 = __builtin_bit_cast(bf16x8,
                    *reinterpret_cast<const u16x8*>(&k2t[(ct*16 + lr) * KSTR + es*32 + lg*8]));
                s1 = __builtin_amdgcn_mfma_f32_16x16x32_bf16(a1[es], b1, s1, 0, 0, 0);
                s2 = __builtin_amdgcn_mfma_f32_16x16x32_bf16(a2[es], b2, s2, 0, 0, 0);
            }
            for (int i = 0; i < 4; ++i) {
                float xa = fminf(fmaxf(s1[i] * CT, -30.f), 30.f);
                float xb = fminf(fmaxf(s2[i] * CS, -30.f), 30.f);
                float t  = __expf(xa);
                float u  = __expf(xb);
                float p  = (t - 1.f) * __builtin_amdgcn_rcpf((t + 1.f) * (1.f + u));
                pt[(w*16 + lg*4 + i) * PSTR + ct*16 + lr] = f2bf(p);
            }
        }
        asm volatile("s_waitcnt lgkmcnt(0)" ::: "memory");
        for (int ks = 0; ks < 2; ++ks) {
            bf16x8 pa = __builtin_bit_cast(bf16x8,
                *reinterpret_cast<const u16x8*>(&pt[(w*16 + lr) * PSTR + ks*32 + lg*8]));
            for (int dt = 0; dt < 4; ++dt) {
                bf16x8 vf = __builtin_bit_cast(bf16x8,
                    *reinterpret_cast<const u16x8*>(&vtt[(dt*16 + lr) * VSTR + ks*32 + lg*8]));
                acc[dt] = __builtin_amdgcn_mfma_f32_16x16x32_bf16(pa, vf, acc[dt], 0, 0, 0);
            }
        }
        __syncthreads();
    }
    const int orow = lblk * 64 + w * 16;
    for (int dt = 0; dt < 4; ++dt)
        for (int i = 0; i < 4; ++i) {
            int l = orow + lg * 4 + i;
            out[((size_t)(b * Lc + l) * Hc + h) * Dc + dt * 16 + lr] = acc[dt][i];
        }
}

extern "C" void kernel_launch(void* const* d_in, const int* in_sizes, int n_in,
                              void* d_out, int out_size, void* d_ws, size_t ws_size,
                              hipStream_t stream) {
    const float* q1 = (const float*)d_in[0];
    const float* k1 = (const float*)d_in[1];
    const float* v1 = (const float*)d_in[2];
    const float* q2 = (const float*)d_in[3];
    const float* k2 = (const float*)d_in[4];
    float* out = (float*)d_out;

    if (ws_size >= WS_NEED) {
        unsigned short* k1b = (unsigned short*)d_ws;
        unsigned short* k2b = k1b + ARR_ELEMS;
        unsigned short* vbp = k2b + ARR_ELEMS;
        prepass_kernel<<<dim3(NBH * TILES), dim3(256), 0, stream>>>(k1, k2, v1, k1b, k2b, vbp);
        fused_kernel<<<dim3(NBH * TILES), dim3(256), 0, stream>>>(q1, q2, k1b, k2b, vbp, out);
    } else {
        fallback_kernel<<<dim3(NBH * TILES), dim3(256), 0, stream>>>(q1, k1, v1, q2, k2, out);
    }
}